// Round 18
// baseline (135.528 us; speedup 1.0000x reference)
//
#include <hip/hip_runtime.h>

// Problem constants: x [32,64,64,64] f32, embed [64,512] f32.
#define N_VEC 131072
#define K 512
#define D 64
#define GUARD 0.05f      // >= 3.8x the derived 2*eps coarse-error requirement
#define NB_GATHER 2048
#define FB_Q 16          // flagged queries per fallback block

typedef __attribute__((ext_vector_type(8))) short bf16x8;  // 8 bf16 = 4 VGPR
typedef __attribute__((ext_vector_type(4))) float f32x4;

static __device__ __forceinline__ short f2bf(float f) {   // RNE
  unsigned u = __builtin_bit_cast(unsigned, f);
  u += 0x7fffu + ((u >> 16) & 1u);
  return (short)(u >> 16);
}
static __device__ __forceinline__ float bf2f(short h) {
  unsigned u = ((unsigned)(unsigned short)h) << 16;
  return __builtin_bit_cast(float, u);
}
static __device__ __forceinline__ void split8(const float4 f0, const float4 f1,
                                              bf16x8& h, bf16x8& m) {
  const float v[8] = {f0.x, f0.y, f0.z, f0.w, f1.x, f1.y, f1.z, f1.w};
#pragma unroll
  for (int j = 0; j < 8; ++j) {
    const short hh = f2bf(v[j]);
    h[j] = hh;
    m[j] = f2bf(v[j] - bf2f(hh));
  }
}

// ---------------------------------------------------------------------------
// Prep (grid 40 x 64): unchanged except cnt[1] (gather counter) also zeroed.
//   blocks 0-31:  pack codebook hi/mid bf16 B-fragments (tile b) into F in
//                 MFMA fragment order: F[b*256 + c*128 + {0|64} + lane].
//   blocks 32-39: et[k][d] fp32 transpose + nrm + counter zeroing.
// ---------------------------------------------------------------------------
__global__ __launch_bounds__(64) void vq_prep_kernel(
    const float* __restrict__ embed, float* __restrict__ et,
    float* __restrict__ nrm, bf16x8* __restrict__ F, int* __restrict__ cnt)
{
  const int b = blockIdx.x;
  const int lane = threadIdx.x;
  if (b < 32) {
    const int row = lane & 15;   // code within tile
    const int kg  = lane >> 4;   // dim-group
    const int code = b * 16 + row;
#pragma unroll
    for (int c = 0; c < 2; ++c) {
      bf16x8 h, m;
#pragma unroll
      for (int j = 0; j < 8; ++j) {
        const int d = kg * 8 + c * 32 + j;
        const float e = embed[d * K + code];
        const short hh = f2bf(e);
        h[j] = hh;
        m[j] = f2bf(e - bf2f(hh));
      }
      F[b * 256 + c * 128 + 0  + lane] = h;
      F[b * 256 + c * 128 + 64 + lane] = m;
    }
  } else {
    if (b == 32 && lane == 0) { cnt[0] = 0; cnt[1] = 0; }
    const int code = (b - 32) * 64 + lane;     // 0..511
    float s = 0.f;
#pragma unroll
    for (int d = 0; d < D; ++d) {
      const float e = embed[d * K + code];
      et[code * D + d] = e;
      s = fmaf(e, e, s);
    }
    nrm[code] = s;
  }
}

// Chain assignment identical to r10-r17 (bit-identical scores):
// P: hh(c0), hh(c1), hm(c0);  Q: hm(c1), mh(c0), mh(c1).
#define MFMA12(P0, Q0, P1, Q1, BH0, BM0, BH1, BM1) do {                        \
    P0 = __builtin_amdgcn_mfma_f32_16x16x32_bf16(Ah0c0, BH0, kZero, 0, 0, 0); \
    P1 = __builtin_amdgcn_mfma_f32_16x16x32_bf16(Ah1c0, BH0, kZero, 0, 0, 0); \
    Q0 = __builtin_amdgcn_mfma_f32_16x16x32_bf16(Ah0c1, BM1, kZero, 0, 0, 0); \
    Q1 = __builtin_amdgcn_mfma_f32_16x16x32_bf16(Ah1c1, BM1, kZero, 0, 0, 0); \
    P0 = __builtin_amdgcn_mfma_f32_16x16x32_bf16(Ah0c1, BH1, P0, 0, 0, 0);    \
    P1 = __builtin_amdgcn_mfma_f32_16x16x32_bf16(Ah1c1, BH1, P1, 0, 0, 0);    \
    Q0 = __builtin_amdgcn_mfma_f32_16x16x32_bf16(Am0c0, BH0, Q0, 0, 0, 0);    \
    Q1 = __builtin_amdgcn_mfma_f32_16x16x32_bf16(Am1c0, BH0, Q1, 0, 0, 0);    \
    P0 = __builtin_amdgcn_mfma_f32_16x16x32_bf16(Ah0c0, BM0, P0, 0, 0, 0);    \
    P1 = __builtin_amdgcn_mfma_f32_16x16x32_bf16(Ah1c0, BM0, P1, 0, 0, 0);    \
    Q0 = __builtin_amdgcn_mfma_f32_16x16x32_bf16(Am0c1, BH1, Q0, 0, 0, 0);    \
    Q1 = __builtin_amdgcn_mfma_f32_16x16x32_bf16(Am1c1, BH1, Q1, 0, 0, 0);    \
  } while (0)

#define SCORE4(P0, Q0, P1, Q1, CODE, NV) do {                                  \
    _Pragma("unroll")                                                          \
    for (int r = 0; r < 4; ++r) {                                              \
      const float s0 = fmaf(-2.f, P0[r], fmaf(-2.f, Q0[r], (NV)));             \
      b2[r] = __builtin_amdgcn_fmed3f(s0, b1[r], b2[r]);                       \
      if (s0 < b1[r]) { b1[r] = s0; i1[r] = (CODE); }                          \
      const float s1 = fmaf(-2.f, P1[r], fmaf(-2.f, Q1[r], (NV)));             \
      b2[4 + r] = __builtin_amdgcn_fmed3f(s1, b1[4 + r], b2[4 + r]);           \
      if (s1 < b1[4 + r]) { b1[4 + r] = s1; i1[4 + r] = (CODE); }              \
    }                                                                          \
  } while (0)

// ---------------------------------------------------------------------------
// Coarse v13 = r17's v12 (passed, 42-44 µs) + s_setprio(1/0) around the MFMA
// cluster (pure scheduling hint; T5 — pays on phase-split schedules).
// Score numerics bit-identical to r10-r17.
// ---------------------------------------------------------------------------
__global__ __attribute__((amdgpu_flat_work_group_size(512, 512),
                          amdgpu_waves_per_eu(2, 4)))
void vq_coarse_kernel(
    const float* __restrict__ x, const bf16x8* __restrict__ F,
    const float* __restrict__ nrm, float* __restrict__ idf,
    int* __restrict__ cnt, int* __restrict__ list)
{
  __shared__ bf16x8 LB[4096];        // 64 KB: one phase (16 tiles)
  __shared__ float nrmL[512];        // 2 KB: all code norms
  const int tid  = threadIdx.x;
  const int lane = tid & 63;
  const int w    = tid >> 6;         // 0..7
  const int row  = lane & 15;
  const int kg   = lane >> 4;
  const int qbase = blockIdx.x * 256 + w * 32;

  if (tid < 512) nrmL[tid] = nrm[tid];   // staged once; barrier below covers

  // A fragments (2 query-sets x 2 K-chunks, hi+mid) — bytes identical r5-r17.
  bf16x8 Ah0c0, Ah0c1, Ah1c0, Ah1c1, Am0c0, Am0c1, Am1c0, Am1c1;
  {
    const float* xr0 = x + (size_t)(qbase + row) * D + kg * 8;
    const float* xr1 = x + (size_t)(qbase + 16 + row) * D + kg * 8;
    split8(*reinterpret_cast<const float4*>(xr0),
           *reinterpret_cast<const float4*>(xr0 + 4), Ah0c0, Am0c0);
    split8(*reinterpret_cast<const float4*>(xr0 + 32),
           *reinterpret_cast<const float4*>(xr0 + 36), Ah0c1, Am0c1);
    split8(*reinterpret_cast<const float4*>(xr1),
           *reinterpret_cast<const float4*>(xr1 + 4), Ah1c0, Am1c0);
    split8(*reinterpret_cast<const float4*>(xr1 + 32),
           *reinterpret_cast<const float4*>(xr1 + 36), Ah1c1, Am1c1);
  }

  float b1[8], b2[8]; int i1[8];   // [s*4+r]
#pragma unroll
  for (int r = 0; r < 8; ++r) { b1[r] = 3.4e38f; b2[r] = 3.4e38f; i1[r] = 0; }

  const f32x4 kZero = {0.f, 0.f, 0.f, 0.f};

#pragma unroll 1
  for (int ph = 0; ph < 2; ++ph) {
    if (ph) __syncthreads();         // phase-0 readers done before overwrite
    {  // stage one phase: 64 KB, 512 thr x 8 x float4 (linear, coalesced)
      const float4* src = reinterpret_cast<const float4*>(F + ph * 4096);
      float4* dst = reinterpret_cast<float4*>(LB);
#pragma unroll
      for (int j = 0; j < 8; ++j) dst[tid + j * 512] = src[tid + j * 512];
    }
    __syncthreads();

#pragma unroll 4
    for (int t = 0; t < 16; ++t) {
      const bf16x8 Bh0 = LB[t * 256 + lane];         // ds_read_b128, imm offs
      const bf16x8 Bm0 = LB[t * 256 + 64 + lane];
      const bf16x8 Bh1 = LB[t * 256 + 128 + lane];
      const bf16x8 Bm1 = LB[t * 256 + 192 + lane];
      const int code = (ph * 16 + t) * 16 + row;
      const float nv = nrmL[code];                   // ds_read_b32 broadcast
      f32x4 p0, q0, p1, q1;
      __builtin_amdgcn_s_setprio(1);
      MFMA12(p0, q0, p1, q1, Bh0, Bm0, Bh1, Bm1);
      __builtin_amdgcn_s_setprio(0);
      SCORE4(p0, q0, p1, q1, code, nv);
    }
  }

  // Butterfly merge across the 16 rows (disjoint code subsets -> exact
  // 1st/2nd of union; cross-row ties -> gap 0 -> flagged -> exact fallback).
#pragma unroll
  for (int m = 1; m < 16; m <<= 1) {
#pragma unroll
    for (int r = 0; r < 8; ++r) {
      const float o1 = __shfl_xor(b1[r], m, 64);
      const int   oi = __shfl_xor(i1[r], m, 64);
      const float o2 = __shfl_xor(b2[r], m, 64);
      if (o1 < b1[r]) { b2[r] = fminf(b1[r], o2); b1[r] = o1; i1[r] = oi; }
      else            { b2[r] = fminf(b2[r], o1); }
    }
  }

  // Id writes + compact flag list (one atomic per wave).
  unsigned m32 = 0;
  if (row == 0) {   // lanes 0,16,32,48: each owns 8 queries (2 sets x 4 regs)
#pragma unroll
    for (int r = 0; r < 8; ++r) {
      const int qoff = (r >> 2) * 16 + kg * 4 + (r & 3);
      idf[qbase + qoff] = (float)i1[r];
      if (b2[r] - b1[r] < GUARD) m32 |= 1u << qoff;
    }
  }
  m32 |= __shfl_xor((int)m32, 16, 64);
  m32 |= __shfl_xor((int)m32, 32, 64);
  if (lane == 0 && m32) {
    int base = atomicAdd(cnt, __popc(m32));
    while (m32) {
      const int b = __ffs(m32) - 1;
      m32 &= m32 - 1;
      list[base++] = qbase + b;
    }
  }
}

// ---------------------------------------------------------------------------
// Fallback v3 (unchanged, proven): exact fp32 rescore, 16 flagged queries per
// block; lane = code, coalesced embed [d][K] reads; numerics bit-identical to
// the round-1 exact path.
// ---------------------------------------------------------------------------
__global__ __launch_bounds__(256) void vq_fallback_kernel(
    const float* __restrict__ x, const float* __restrict__ embed,
    const float* __restrict__ nrm, const int* __restrict__ cnt,
    const int* __restrict__ list, float* __restrict__ idf)
{
  __shared__ float x_lds[FB_Q * D];   // 4 KB
  __shared__ int   s_qidx[FB_Q];
  __shared__ float s_best[4][FB_Q];
  __shared__ int   s_bid[4][FB_Q];
  const int tid  = threadIdx.x;
  const int lane = tid & 63;
  const int wv   = tid >> 6;          // 0..3: codes wv*128 + {lane, lane+64}
  const int n = cnt[0];

  for (int qb = blockIdx.x * FB_Q; qb < n; qb += gridDim.x * FB_Q) {
    __syncthreads();   // previous batch's epilogue reads done before overwrite
    if (tid < FB_Q) {
      const int idx = qb + tid;
      s_qidx[tid] = list[idx < n ? idx : qb];  // pad with first-of-batch (dup-safe)
    }
    __syncthreads();
    {  // stage x rows: 16 q x 16 float4 = 256 loads, 1 per thread
      const int qj = tid >> 4, dq = tid & 15;
      *reinterpret_cast<float4*>(&x_lds[qj * D + dq * 4]) =
          *reinterpret_cast<const float4*>(x + (size_t)s_qidx[qj] * D + dq * 4);
    }
    __syncthreads();

    const int c0 = wv * 128 + lane;
    const int c1 = c0 + 64;
    float a0[FB_Q], a1[FB_Q];
#pragma unroll
    for (int i = 0; i < FB_Q; ++i) { a0[i] = 0.f; a1[i] = 0.f; }

#pragma unroll 4
    for (int ch = 0; ch < 16; ++ch) {   // 4 dims per chunk, d ascending
      const int d0 = ch * 4;
      const float e00 = embed[(d0 + 0) * K + c0];
      const float e01 = embed[(d0 + 0) * K + c1];
      const float e10 = embed[(d0 + 1) * K + c0];
      const float e11 = embed[(d0 + 1) * K + c1];
      const float e20 = embed[(d0 + 2) * K + c0];
      const float e21 = embed[(d0 + 2) * K + c1];
      const float e30 = embed[(d0 + 3) * K + c0];
      const float e31 = embed[(d0 + 3) * K + c1];
#pragma unroll
      for (int i = 0; i < FB_Q; ++i) {
        const float4 xv = *reinterpret_cast<const float4*>(&x_lds[i * D + d0]);
        a0[i] = fmaf(xv.x, e00, a0[i]);
        a0[i] = fmaf(xv.y, e10, a0[i]);
        a0[i] = fmaf(xv.z, e20, a0[i]);
        a0[i] = fmaf(xv.w, e30, a0[i]);
        a1[i] = fmaf(xv.x, e01, a1[i]);
        a1[i] = fmaf(xv.y, e11, a1[i]);
        a1[i] = fmaf(xv.z, e21, a1[i]);
        a1[i] = fmaf(xv.w, e31, a1[i]);
      }
    }

    const float nr0 = nrm[c0], nr1 = nrm[c1];
#pragma unroll
    for (int i = 0; i < FB_Q; ++i) {
      float best; int bid;
      const float s0 = fmaf(-2.f, a0[i], nr0);
      best = s0; bid = c0;                      // c0 < c1, visited first
      const float s1 = fmaf(-2.f, a1[i], nr1);
      if (s1 < best) { best = s1; bid = c1; }
#pragma unroll
      for (int off = 32; off > 0; off >>= 1) {
        const float s2 = __shfl_down(best, off, 64);
        const int   b2 = __shfl_down(bid, off, 64);
        if (s2 < best || (s2 == best && b2 < bid)) { best = s2; bid = b2; }
      }
      if (lane == 0) { s_best[wv][i] = best; s_bid[wv][i] = bid; }
    }
    __syncthreads();
    if (tid < FB_Q) {   // merge 4 waves, ascending wv = ascending code range
      float best = s_best[0][tid]; int bid = s_bid[0][tid];
#pragma unroll
      for (int w = 1; w < 4; ++w) {
        const float s = s_best[w][tid];
        if (s < best) { best = s; bid = s_bid[w][tid]; }  // tie keeps lower k
      }
      idf[s_qidx[tid]] = (float)bid;
    }
  }
}

// ---------------------------------------------------------------------------
// Gather + finalize (fused): q = et[id], diff partials, then the LAST block
// (device-scope counter) sums all partials in FIXED order -> deterministic
// diff, saving one kernel launch.
// ---------------------------------------------------------------------------
__global__ __launch_bounds__(256) void vq_gather_kernel(
    const float* __restrict__ x, const float* __restrict__ et,
    const float* __restrict__ idf, float* __restrict__ q,
    float* __restrict__ partial, int* __restrict__ gcnt,
    float* __restrict__ diff)
{
  const int tid = blockIdx.x * 256 + threadIdx.x;
  const int stride = gridDim.x * 256;
  float acc = 0.f;
  for (int idx = tid; idx < N_VEC * (D / 4); idx += stride) {
    const int v = idx >> 4;
    const int d4 = idx & 15;
    const int id = (int)idf[v];
    const float4 xv = reinterpret_cast<const float4*>(x)[idx];
    const float4 ev = reinterpret_cast<const float4*>(et)[(id << 4) + d4];
    const float e0 = ev.x - xv.x, e1 = ev.y - xv.y, e2 = ev.z - xv.z, e3 = ev.w - xv.w;
    acc += (e0 * e0 + e1 * e1) + (e2 * e2 + e3 * e3);
    reinterpret_cast<float4*>(q)[idx] = ev;
  }
  acc += __shfl_down(acc, 32, 64);
  acc += __shfl_down(acc, 16, 64);
  acc += __shfl_down(acc, 8, 64);
  acc += __shfl_down(acc, 4, 64);
  acc += __shfl_down(acc, 2, 64);
  acc += __shfl_down(acc, 1, 64);
  __shared__ float sred[4];
  __shared__ bool amLast;
  if ((threadIdx.x & 63) == 0) sred[threadIdx.x >> 6] = acc;
  __syncthreads();
  if (threadIdx.x == 0) {
    partial[blockIdx.x] = (sred[0] + sred[1]) + (sred[2] + sred[3]);
    __threadfence();                                  // partial visible device-wide
    amLast = (atomicAdd(gcnt, 1) == NB_GATHER - 1);   // before my increment lands
  }
  __syncthreads();
  if (amLast) {
    __threadfence();   // all other blocks' partials now visible
    float a2 = 0.f;
    for (int i = threadIdx.x; i < NB_GATHER; i += 256) a2 += partial[i];
    a2 += __shfl_down(a2, 32, 64);
    a2 += __shfl_down(a2, 16, 64);
    a2 += __shfl_down(a2, 8, 64);
    a2 += __shfl_down(a2, 4, 64);
    a2 += __shfl_down(a2, 2, 64);
    a2 += __shfl_down(a2, 1, 64);
    __syncthreads();   // sred reuse safe
    if ((threadIdx.x & 63) == 0) sred[threadIdx.x >> 6] = a2;
    __syncthreads();
    if (threadIdx.x == 0)
      diff[0] = ((sred[0] + sred[1]) + (sred[2] + sred[3])) *
                (1.0f / (float)(N_VEC * D));
  }
}

extern "C" void kernel_launch(void* const* d_in, const int* in_sizes, int n_in,
                              void* d_out, int out_size, void* d_ws, size_t ws_size,
                              hipStream_t stream) {
  const float* x = (const float*)d_in[0];
  const float* embed = (const float*)d_in[1];
  float* out = (float*)d_out;
  float* q    = out;                 // [0, 8388608): q_st
  float* diff = out + 8388608;       // commitment loss scalar
  float* idf  = out + 8388609;       // emd_id as float [131072]

  float* ws = (float*)d_ws;          // layout (float idx):
  float* et      = ws;               // [0, 32768)       fp32 codebook rows
  float* nrm     = ws + 32768;       // [32768, 33312)   512 norms + 32 pad
  float* partial = ws + 33312;       // [33312, 35360)   diff partials
  int*   cnt     = (int*)(ws + 35360);         // [0]=flag cnt, [1]=gather cnt
  int*   list    = (int*)(ws + 35368);         // flagged query indices
  bf16x8* F = (bf16x8*)(ws + 35368 + N_VEC);   // 128 KB packed hi/mid B-frags

  vq_prep_kernel<<<40, 64, 0, stream>>>(embed, et, nrm, F, cnt);
  vq_coarse_kernel<<<N_VEC / 256, 512, 0, stream>>>(x, F, nrm, idf, cnt, list);
  vq_fallback_kernel<<<1024, 256, 0, stream>>>(x, embed, nrm, cnt, list, idf);
  vq_gather_kernel<<<NB_GATHER, 256, 0, stream>>>(x, et, idf, q, partial,
                                                  cnt + 1, diff);
}

// Round 19
// 81.511 us; speedup vs baseline: 1.6627x; 1.6627x over previous
//
#include <hip/hip_runtime.h>

// Problem constants: x [32,64,64,64] f32, embed [64,512] f32.
#define N_VEC 131072
#define K 512
#define D 64
#define GUARD 0.05f      // >= 3.8x the derived 2*eps coarse-error requirement
#define NB_GATHER 2048
#define FB_Q 16          // flagged queries per fallback block

typedef __attribute__((ext_vector_type(8))) short bf16x8;  // 8 bf16 = 4 VGPR
typedef __attribute__((ext_vector_type(4))) float f32x4;

static __device__ __forceinline__ short f2bf(float f) {   // RNE
  unsigned u = __builtin_bit_cast(unsigned, f);
  u += 0x7fffu + ((u >> 16) & 1u);
  return (short)(u >> 16);
}
static __device__ __forceinline__ float bf2f(short h) {
  unsigned u = ((unsigned)(unsigned short)h) << 16;
  return __builtin_bit_cast(float, u);
}
static __device__ __forceinline__ void split8(const float4 f0, const float4 f1,
                                              bf16x8& h, bf16x8& m) {
  const float v[8] = {f0.x, f0.y, f0.z, f0.w, f1.x, f1.y, f1.z, f1.w};
#pragma unroll
  for (int j = 0; j < 8; ++j) {
    const short hh = f2bf(v[j]);
    h[j] = hh;
    m[j] = f2bf(v[j] - bf2f(hh));
  }
}

// ---------------------------------------------------------------------------
// Prep (grid 40 x 64): unchanged (proven r10-r18).
//   blocks 0-31:  pack codebook hi/mid bf16 B-fragments (tile b) into F in
//                 MFMA fragment order: F[b*256 + c*128 + {0|64} + lane].
//   blocks 32-39: et[k][d] fp32 transpose + nrm + flag-counter zeroing.
// ---------------------------------------------------------------------------
__global__ __launch_bounds__(64) void vq_prep_kernel(
    const float* __restrict__ embed, float* __restrict__ et,
    float* __restrict__ nrm, bf16x8* __restrict__ F, int* __restrict__ cnt)
{
  const int b = blockIdx.x;
  const int lane = threadIdx.x;
  if (b < 32) {
    const int row = lane & 15;   // code within tile
    const int kg  = lane >> 4;   // dim-group
    const int code = b * 16 + row;
#pragma unroll
    for (int c = 0; c < 2; ++c) {
      bf16x8 h, m;
#pragma unroll
      for (int j = 0; j < 8; ++j) {
        const int d = kg * 8 + c * 32 + j;
        const float e = embed[d * K + code];
        const short hh = f2bf(e);
        h[j] = hh;
        m[j] = f2bf(e - bf2f(hh));
      }
      F[b * 256 + c * 128 + 0  + lane] = h;
      F[b * 256 + c * 128 + 64 + lane] = m;
    }
  } else {
    if (b == 32 && lane == 0) cnt[0] = 0;
    const int code = (b - 32) * 64 + lane;     // 0..511
    float s = 0.f;
#pragma unroll
    for (int d = 0; d < D; ++d) {
      const float e = embed[d * K + code];
      et[code * D + d] = e;
      s = fmaf(e, e, s);
    }
    nrm[code] = s;
  }
}

// Chain assignment identical to r10-r18 (bit-identical scores):
// P: hh(c0), hh(c1), hm(c0);  Q: hm(c1), mh(c0), mh(c1).
#define MFMA12(P0, Q0, P1, Q1, BH0, BM0, BH1, BM1) do {                        \
    P0 = __builtin_amdgcn_mfma_f32_16x16x32_bf16(Ah0c0, BH0, kZero, 0, 0, 0); \
    P1 = __builtin_amdgcn_mfma_f32_16x16x32_bf16(Ah1c0, BH0, kZero, 0, 0, 0); \
    Q0 = __builtin_amdgcn_mfma_f32_16x16x32_bf16(Ah0c1, BM1, kZero, 0, 0, 0); \
    Q1 = __builtin_amdgcn_mfma_f32_16x16x32_bf16(Ah1c1, BM1, kZero, 0, 0, 0); \
    P0 = __builtin_amdgcn_mfma_f32_16x16x32_bf16(Ah0c1, BH1, P0, 0, 0, 0);    \
    P1 = __builtin_amdgcn_mfma_f32_16x16x32_bf16(Ah1c1, BH1, P1, 0, 0, 0);    \
    Q0 = __builtin_amdgcn_mfma_f32_16x16x32_bf16(Am0c0, BH0, Q0, 0, 0, 0);    \
    Q1 = __builtin_amdgcn_mfma_f32_16x16x32_bf16(Am1c0, BH0, Q1, 0, 0, 0);    \
    P0 = __builtin_amdgcn_mfma_f32_16x16x32_bf16(Ah0c0, BM0, P0, 0, 0, 0);    \
    P1 = __builtin_amdgcn_mfma_f32_16x16x32_bf16(Ah1c0, BM0, P1, 0, 0, 0);    \
    Q0 = __builtin_amdgcn_mfma_f32_16x16x32_bf16(Am0c1, BH1, Q0, 0, 0, 0);    \
    Q1 = __builtin_amdgcn_mfma_f32_16x16x32_bf16(Am1c1, BH1, Q1, 0, 0, 0);    \
  } while (0)

#define SCORE4(P0, Q0, P1, Q1, CODE, NV) do {                                  \
    _Pragma("unroll")                                                          \
    for (int r = 0; r < 4; ++r) {                                              \
      const float s0 = fmaf(-2.f, P0[r], fmaf(-2.f, Q0[r], (NV)));             \
      b2[r] = __builtin_amdgcn_fmed3f(s0, b1[r], b2[r]);                       \
      if (s0 < b1[r]) { b1[r] = s0; i1[r] = (CODE); }                          \
      const float s1 = fmaf(-2.f, P1[r], fmaf(-2.f, Q1[r], (NV)));             \
      b2[4 + r] = __builtin_amdgcn_fmed3f(s1, b1[4 + r], b2[4 + r]);           \
      if (s1 < b1[4 + r]) { b1[4 + r] = s1; i1[4 + r] = (CODE); }              \
    }                                                                          \
  } while (0)

// ---------------------------------------------------------------------------
// Coarse v13 (as r18, kept): r17's v12 + s_setprio(1/0) around the MFMA
// cluster. This round's counters attribute the setprio delta cleanly vs
// r17's 42.4-44.3 µs (r18's gather regression swamped the total).
// Score numerics bit-identical to r10-r18 (passed).
// ---------------------------------------------------------------------------
__global__ __attribute__((amdgpu_flat_work_group_size(512, 512),
                          amdgpu_waves_per_eu(2, 4)))
void vq_coarse_kernel(
    const float* __restrict__ x, const bf16x8* __restrict__ F,
    const float* __restrict__ nrm, float* __restrict__ idf,
    int* __restrict__ cnt, int* __restrict__ list)
{
  __shared__ bf16x8 LB[4096];        // 64 KB: one phase (16 tiles)
  __shared__ float nrmL[512];        // 2 KB: all code norms
  const int tid  = threadIdx.x;
  const int lane = tid & 63;
  const int w    = tid >> 6;         // 0..7
  const int row  = lane & 15;
  const int kg   = lane >> 4;
  const int qbase = blockIdx.x * 256 + w * 32;

  if (tid < 512) nrmL[tid] = nrm[tid];   // staged once; barrier below covers

  // A fragments (2 query-sets x 2 K-chunks, hi+mid) — bytes identical r5-r18.
  bf16x8 Ah0c0, Ah0c1, Ah1c0, Ah1c1, Am0c0, Am0c1, Am1c0, Am1c1;
  {
    const float* xr0 = x + (size_t)(qbase + row) * D + kg * 8;
    const float* xr1 = x + (size_t)(qbase + 16 + row) * D + kg * 8;
    split8(*reinterpret_cast<const float4*>(xr0),
           *reinterpret_cast<const float4*>(xr0 + 4), Ah0c0, Am0c0);
    split8(*reinterpret_cast<const float4*>(xr0 + 32),
           *reinterpret_cast<const float4*>(xr0 + 36), Ah0c1, Am0c1);
    split8(*reinterpret_cast<const float4*>(xr1),
           *reinterpret_cast<const float4*>(xr1 + 4), Ah1c0, Am1c0);
    split8(*reinterpret_cast<const float4*>(xr1 + 32),
           *reinterpret_cast<const float4*>(xr1 + 36), Ah1c1, Am1c1);
  }

  float b1[8], b2[8]; int i1[8];   // [s*4+r]
#pragma unroll
  for (int r = 0; r < 8; ++r) { b1[r] = 3.4e38f; b2[r] = 3.4e38f; i1[r] = 0; }

  const f32x4 kZero = {0.f, 0.f, 0.f, 0.f};

#pragma unroll 1
  for (int ph = 0; ph < 2; ++ph) {
    if (ph) __syncthreads();         // phase-0 readers done before overwrite
    {  // stage one phase: 64 KB, 512 thr x 8 x float4 (linear, coalesced)
      const float4* src = reinterpret_cast<const float4*>(F + ph * 4096);
      float4* dst = reinterpret_cast<float4*>(LB);
#pragma unroll
      for (int j = 0; j < 8; ++j) dst[tid + j * 512] = src[tid + j * 512];
    }
    __syncthreads();

#pragma unroll 4
    for (int t = 0; t < 16; ++t) {
      const bf16x8 Bh0 = LB[t * 256 + lane];         // ds_read_b128, imm offs
      const bf16x8 Bm0 = LB[t * 256 + 64 + lane];
      const bf16x8 Bh1 = LB[t * 256 + 128 + lane];
      const bf16x8 Bm1 = LB[t * 256 + 192 + lane];
      const int code = (ph * 16 + t) * 16 + row;
      const float nv = nrmL[code];                   // ds_read_b32 broadcast
      f32x4 p0, q0, p1, q1;
      __builtin_amdgcn_s_setprio(1);
      MFMA12(p0, q0, p1, q1, Bh0, Bm0, Bh1, Bm1);
      __builtin_amdgcn_s_setprio(0);
      SCORE4(p0, q0, p1, q1, code, nv);
    }
  }

  // Butterfly merge across the 16 rows (disjoint code subsets -> exact
  // 1st/2nd of union; cross-row ties -> gap 0 -> flagged -> exact fallback).
#pragma unroll
  for (int m = 1; m < 16; m <<= 1) {
#pragma unroll
    for (int r = 0; r < 8; ++r) {
      const float o1 = __shfl_xor(b1[r], m, 64);
      const int   oi = __shfl_xor(i1[r], m, 64);
      const float o2 = __shfl_xor(b2[r], m, 64);
      if (o1 < b1[r]) { b2[r] = fminf(b1[r], o2); b1[r] = o1; i1[r] = oi; }
      else            { b2[r] = fminf(b2[r], o1); }
    }
  }

  // Id writes + compact flag list (one atomic per wave).
  unsigned m32 = 0;
  if (row == 0) {   // lanes 0,16,32,48: each owns 8 queries (2 sets x 4 regs)
#pragma unroll
    for (int r = 0; r < 8; ++r) {
      const int qoff = (r >> 2) * 16 + kg * 4 + (r & 3);
      idf[qbase + qoff] = (float)i1[r];
      if (b2[r] - b1[r] < GUARD) m32 |= 1u << qoff;
    }
  }
  m32 |= __shfl_xor((int)m32, 16, 64);
  m32 |= __shfl_xor((int)m32, 32, 64);
  if (lane == 0 && m32) {
    int base = atomicAdd(cnt, __popc(m32));
    while (m32) {
      const int b = __ffs(m32) - 1;
      m32 &= m32 - 1;
      list[base++] = qbase + b;
    }
  }
}

// ---------------------------------------------------------------------------
// Fallback v3 (unchanged, proven): exact fp32 rescore, 16 flagged queries per
// block; lane = code, coalesced embed [d][K] reads; numerics bit-identical to
// the round-1 exact path.
// ---------------------------------------------------------------------------
__global__ __launch_bounds__(256) void vq_fallback_kernel(
    const float* __restrict__ x, const float* __restrict__ embed,
    const float* __restrict__ nrm, const int* __restrict__ cnt,
    const int* __restrict__ list, float* __restrict__ idf)
{
  __shared__ float x_lds[FB_Q * D];   // 4 KB
  __shared__ int   s_qidx[FB_Q];
  __shared__ float s_best[4][FB_Q];
  __shared__ int   s_bid[4][FB_Q];
  const int tid  = threadIdx.x;
  const int lane = tid & 63;
  const int wv   = tid >> 6;          // 0..3: codes wv*128 + {lane, lane+64}
  const int n = cnt[0];

  for (int qb = blockIdx.x * FB_Q; qb < n; qb += gridDim.x * FB_Q) {
    __syncthreads();   // previous batch's epilogue reads done before overwrite
    if (tid < FB_Q) {
      const int idx = qb + tid;
      s_qidx[tid] = list[idx < n ? idx : qb];  // pad with first-of-batch (dup-safe)
    }
    __syncthreads();
    {  // stage x rows: 16 q x 16 float4 = 256 loads, 1 per thread
      const int qj = tid >> 4, dq = tid & 15;
      *reinterpret_cast<float4*>(&x_lds[qj * D + dq * 4]) =
          *reinterpret_cast<const float4*>(x + (size_t)s_qidx[qj] * D + dq * 4);
    }
    __syncthreads();

    const int c0 = wv * 128 + lane;
    const int c1 = c0 + 64;
    float a0[FB_Q], a1[FB_Q];
#pragma unroll
    for (int i = 0; i < FB_Q; ++i) { a0[i] = 0.f; a1[i] = 0.f; }

#pragma unroll 4
    for (int ch = 0; ch < 16; ++ch) {   // 4 dims per chunk, d ascending
      const int d0 = ch * 4;
      const float e00 = embed[(d0 + 0) * K + c0];
      const float e01 = embed[(d0 + 0) * K + c1];
      const float e10 = embed[(d0 + 1) * K + c0];
      const float e11 = embed[(d0 + 1) * K + c1];
      const float e20 = embed[(d0 + 2) * K + c0];
      const float e21 = embed[(d0 + 2) * K + c1];
      const float e30 = embed[(d0 + 3) * K + c0];
      const float e31 = embed[(d0 + 3) * K + c1];
#pragma unroll
      for (int i = 0; i < FB_Q; ++i) {
        const float4 xv = *reinterpret_cast<const float4*>(&x_lds[i * D + d0]);
        a0[i] = fmaf(xv.x, e00, a0[i]);
        a0[i] = fmaf(xv.y, e10, a0[i]);
        a0[i] = fmaf(xv.z, e20, a0[i]);
        a0[i] = fmaf(xv.w, e30, a0[i]);
        a1[i] = fmaf(xv.x, e01, a1[i]);
        a1[i] = fmaf(xv.y, e11, a1[i]);
        a1[i] = fmaf(xv.z, e21, a1[i]);
        a1[i] = fmaf(xv.w, e31, a1[i]);
      }
    }

    const float nr0 = nrm[c0], nr1 = nrm[c1];
#pragma unroll
    for (int i = 0; i < FB_Q; ++i) {
      float best; int bid;
      const float s0 = fmaf(-2.f, a0[i], nr0);
      best = s0; bid = c0;                      // c0 < c1, visited first
      const float s1 = fmaf(-2.f, a1[i], nr1);
      if (s1 < best) { best = s1; bid = c1; }
#pragma unroll
      for (int off = 32; off > 0; off >>= 1) {
        const float s2 = __shfl_down(best, off, 64);
        const int   b2 = __shfl_down(bid, off, 64);
        if (s2 < best || (s2 == best && b2 < bid)) { best = s2; bid = b2; }
      }
      if (lane == 0) { s_best[wv][i] = best; s_bid[wv][i] = bid; }
    }
    __syncthreads();
    if (tid < FB_Q) {   // merge 4 waves, ascending wv = ascending code range
      float best = s_best[0][tid]; int bid = s_bid[0][tid];
#pragma unroll
      for (int w = 1; w < 4; ++w) {
        const float s = s_best[w][tid];
        if (s < best) { best = s; bid = s_bid[w][tid]; }  // tie keeps lower k
      }
      idf[s_qidx[tid]] = (float)bid;
    }
  }
}

// ---------------------------------------------------------------------------
// Gather (r17 version, proven 13 µs): q = et[id], write q_st, diff partials.
// ---------------------------------------------------------------------------
__global__ __launch_bounds__(256) void vq_gather_kernel(
    const float* __restrict__ x, const float* __restrict__ et,
    const float* __restrict__ idf, float* __restrict__ q,
    float* __restrict__ partial)
{
  const int tid = blockIdx.x * 256 + threadIdx.x;
  const int stride = gridDim.x * 256;
  float acc = 0.f;
  for (int idx = tid; idx < N_VEC * (D / 4); idx += stride) {
    const int v = idx >> 4;
    const int d4 = idx & 15;
    const int id = (int)idf[v];
    const float4 xv = reinterpret_cast<const float4*>(x)[idx];
    const float4 ev = reinterpret_cast<const float4*>(et)[(id << 4) + d4];
    const float e0 = ev.x - xv.x, e1 = ev.y - xv.y, e2 = ev.z - xv.z, e3 = ev.w - xv.w;
    acc += (e0 * e0 + e1 * e1) + (e2 * e2 + e3 * e3);
    reinterpret_cast<float4*>(q)[idx] = ev;
  }
  acc += __shfl_down(acc, 32, 64);
  acc += __shfl_down(acc, 16, 64);
  acc += __shfl_down(acc, 8, 64);
  acc += __shfl_down(acc, 4, 64);
  acc += __shfl_down(acc, 2, 64);
  acc += __shfl_down(acc, 1, 64);
  __shared__ float sred[4];
  if ((threadIdx.x & 63) == 0) sred[threadIdx.x >> 6] = acc;
  __syncthreads();
  if (threadIdx.x == 0)
    partial[blockIdx.x] = (sred[0] + sred[1]) + (sred[2] + sred[3]);
}

__global__ __launch_bounds__(256) void vq_finalize_kernel(
    const float* __restrict__ partial, float* __restrict__ out)
{
  float acc = 0.f;
  for (int i = threadIdx.x; i < NB_GATHER; i += 256) acc += partial[i];
  acc += __shfl_down(acc, 32, 64);
  acc += __shfl_down(acc, 16, 64);
  acc += __shfl_down(acc, 8, 64);
  acc += __shfl_down(acc, 4, 64);
  acc += __shfl_down(acc, 2, 64);
  acc += __shfl_down(acc, 1, 64);
  __shared__ float sred[4];
  if ((threadIdx.x & 63) == 0) sred[threadIdx.x >> 6] = acc;
  __syncthreads();
  if (threadIdx.x == 0)
    out[0] = ((sred[0] + sred[1]) + (sred[2] + sred[3])) * (1.0f / (float)(N_VEC * D));
}

extern "C" void kernel_launch(void* const* d_in, const int* in_sizes, int n_in,
                              void* d_out, int out_size, void* d_ws, size_t ws_size,
                              hipStream_t stream) {
  const float* x = (const float*)d_in[0];
  const float* embed = (const float*)d_in[1];
  float* out = (float*)d_out;
  float* q    = out;                 // [0, 8388608): q_st
  float* diff = out + 8388608;       // commitment loss scalar
  float* idf  = out + 8388609;       // emd_id as float [131072]

  float* ws = (float*)d_ws;          // layout (float idx):
  float* et      = ws;               // [0, 32768)       fp32 codebook rows
  float* nrm     = ws + 32768;       // [32768, 33312)   512 norms + 32 pad
  float* partial = ws + 33312;       // [33312, 35360)   diff partials
  int*   cnt     = (int*)(ws + 35360);         // flag counter
  int*   list    = (int*)(ws + 35368);         // flagged query indices
  bf16x8* F = (bf16x8*)(ws + 35368 + N_VEC);   // 128 KB packed hi/mid B-frags

  vq_prep_kernel<<<40, 64, 0, stream>>>(embed, et, nrm, F, cnt);
  vq_coarse_kernel<<<N_VEC / 256, 512, 0, stream>>>(x, F, nrm, idf, cnt, list);
  vq_fallback_kernel<<<1024, 256, 0, stream>>>(x, embed, nrm, cnt, list, idf);
  vq_gather_kernel<<<NB_GATHER, 256, 0, stream>>>(x, et, idf, q, partial);
  vq_finalize_kernel<<<1, 256, 0, stream>>>(partial, diff);
}

// Round 20
// 77.776 us; speedup vs baseline: 1.7425x; 1.0480x over previous
//
#include <hip/hip_runtime.h>

// Problem constants: x [32,64,64,64] f32, embed [64,512] f32.
#define N_VEC 131072
#define K 512
#define D 64
#define GUARD 0.02f      // f16 split: eps ~1.5e-3, 2*eps ~3e-3 -> 6x margin
#define NB_GATHER 2048
#define FB_Q 16          // flagged queries per fallback block

typedef __attribute__((ext_vector_type(8))) _Float16 f16x8;  // 8 f16 = 4 VGPR
typedef __attribute__((ext_vector_type(4))) float f32x4;

// fp16 hi/mid split: h = RNE(f), m = RNE(f - h). Dropped terms in the
// 3-product reconstruction are O(2^-22) -- far below bf16's O(2^-16).
static __device__ __forceinline__ void split8(const float4 f0, const float4 f1,
                                              f16x8& h, f16x8& m) {
  const float v[8] = {f0.x, f0.y, f0.z, f0.w, f1.x, f1.y, f1.z, f1.w};
#pragma unroll
  for (int j = 0; j < 8; ++j) {
    const _Float16 hh = (_Float16)v[j];
    h[j] = hh;
    m[j] = (_Float16)(v[j] - (float)hh);
  }
}

// ---------------------------------------------------------------------------
// Prep (grid 40 x 64): structure unchanged (proven r10-r19); F now holds f16
// hi/mid fragments (same layout/bytes: F[b*256 + c*128 + {0|64} + lane]).
//   blocks 32-39: et[k][d] fp32 transpose + nrm + flag-counter zeroing.
// ---------------------------------------------------------------------------
__global__ __launch_bounds__(64) void vq_prep_kernel(
    const float* __restrict__ embed, float* __restrict__ et,
    float* __restrict__ nrm, f16x8* __restrict__ F, int* __restrict__ cnt)
{
  const int b = blockIdx.x;
  const int lane = threadIdx.x;
  if (b < 32) {
    const int row = lane & 15;   // code within tile
    const int kg  = lane >> 4;   // dim-group
    const int code = b * 16 + row;
#pragma unroll
    for (int c = 0; c < 2; ++c) {
      f16x8 h, m;
#pragma unroll
      for (int j = 0; j < 8; ++j) {
        const int d = kg * 8 + c * 32 + j;
        const float e = embed[d * K + code];
        const _Float16 hh = (_Float16)e;
        h[j] = hh;
        m[j] = (_Float16)(e - (float)hh);
      }
      F[b * 256 + c * 128 + 0  + lane] = h;
      F[b * 256 + c * 128 + 64 + lane] = m;
    }
  } else {
    if (b == 32 && lane == 0) cnt[0] = 0;
    const int code = (b - 32) * 64 + lane;     // 0..511
    float s = 0.f;
#pragma unroll
    for (int d = 0; d < D; ++d) {
      const float e = embed[d * K + code];
      et[code * D + d] = e;
      s = fmaf(e, e, s);
    }
    nrm[code] = s;
  }
}

// Chain assignment as r10-r19 (hh/hm/mh over 2 K-chunks x 2 query-sets),
// now on the f16 MFMA (same shape/layout/cost):
// P: hh(c0), hh(c1), hm(c0);  Q: hm(c1), mh(c0), mh(c1).
#define MFMA12(P0, Q0, P1, Q1, BH0, BM0, BH1, BM1) do {                        \
    P0 = __builtin_amdgcn_mfma_f32_16x16x32_f16(Ah0c0, BH0, kZero, 0, 0, 0);  \
    P1 = __builtin_amdgcn_mfma_f32_16x16x32_f16(Ah1c0, BH0, kZero, 0, 0, 0);  \
    Q0 = __builtin_amdgcn_mfma_f32_16x16x32_f16(Ah0c1, BM1, kZero, 0, 0, 0);  \
    Q1 = __builtin_amdgcn_mfma_f32_16x16x32_f16(Ah1c1, BM1, kZero, 0, 0, 0);  \
    P0 = __builtin_amdgcn_mfma_f32_16x16x32_f16(Ah0c1, BH1, P0, 0, 0, 0);     \
    P1 = __builtin_amdgcn_mfma_f32_16x16x32_f16(Ah1c1, BH1, P1, 0, 0, 0);     \
    Q0 = __builtin_amdgcn_mfma_f32_16x16x32_f16(Am0c0, BH0, Q0, 0, 0, 0);     \
    Q1 = __builtin_amdgcn_mfma_f32_16x16x32_f16(Am1c0, BH0, Q1, 0, 0, 0);     \
    P0 = __builtin_amdgcn_mfma_f32_16x16x32_f16(Ah0c0, BM0, P0, 0, 0, 0);     \
    P1 = __builtin_amdgcn_mfma_f32_16x16x32_f16(Ah1c0, BM0, P1, 0, 0, 0);     \
    Q0 = __builtin_amdgcn_mfma_f32_16x16x32_f16(Am0c1, BH1, Q0, 0, 0, 0);     \
    Q1 = __builtin_amdgcn_mfma_f32_16x16x32_f16(Am1c1, BH1, Q1, 0, 0, 0);     \
  } while (0)

#define SCORE4(P0, Q0, P1, Q1, CODE, NV) do {                                  \
    _Pragma("unroll")                                                          \
    for (int r = 0; r < 4; ++r) {                                              \
      const float s0 = fmaf(-2.f, P0[r], fmaf(-2.f, Q0[r], (NV)));             \
      b2[r] = __builtin_amdgcn_fmed3f(s0, b1[r], b2[r]);                       \
      if (s0 < b1[r]) { b1[r] = s0; i1[r] = (CODE); }                          \
      const float s1 = fmaf(-2.f, P1[r], fmaf(-2.f, Q1[r], (NV)));             \
      b2[4 + r] = __builtin_amdgcn_fmed3f(s1, b1[4 + r], b2[4 + r]);           \
      if (s1 < b1[4 + r]) { b1[4 + r] = s1; i1[4 + r] = (CODE); }              \
    }                                                                          \
  } while (0)

// ---------------------------------------------------------------------------
// Coarse v14 = r19's v13 with the f16 split (GUARD 0.02). Structure, LDS
// phases, setprio, merge, flag list all byte-identical to r19 (passed).
// Unflagged correctness: gap >= GUARD > 2*eps(f16) -> coarse argmin = exact
// argmin; exact ties -> coarse gap <= 2*eps < GUARD -> flagged -> exact
// fallback applies numpy's first-min tie-break.
// ---------------------------------------------------------------------------
__global__ __attribute__((amdgpu_flat_work_group_size(512, 512),
                          amdgpu_waves_per_eu(2, 4)))
void vq_coarse_kernel(
    const float* __restrict__ x, const f16x8* __restrict__ F,
    const float* __restrict__ nrm, float* __restrict__ idf,
    int* __restrict__ cnt, int* __restrict__ list)
{
  __shared__ f16x8 LB[4096];         // 64 KB: one phase (16 tiles)
  __shared__ float nrmL[512];        // 2 KB: all code norms
  const int tid  = threadIdx.x;
  const int lane = tid & 63;
  const int w    = tid >> 6;         // 0..7
  const int row  = lane & 15;
  const int kg   = lane >> 4;
  const int qbase = blockIdx.x * 256 + w * 32;

  if (tid < 512) nrmL[tid] = nrm[tid];   // staged once; barrier below covers

  // A fragments (2 query-sets x 2 K-chunks, f16 hi+mid).
  f16x8 Ah0c0, Ah0c1, Ah1c0, Ah1c1, Am0c0, Am0c1, Am1c0, Am1c1;
  {
    const float* xr0 = x + (size_t)(qbase + row) * D + kg * 8;
    const float* xr1 = x + (size_t)(qbase + 16 + row) * D + kg * 8;
    split8(*reinterpret_cast<const float4*>(xr0),
           *reinterpret_cast<const float4*>(xr0 + 4), Ah0c0, Am0c0);
    split8(*reinterpret_cast<const float4*>(xr0 + 32),
           *reinterpret_cast<const float4*>(xr0 + 36), Ah0c1, Am0c1);
    split8(*reinterpret_cast<const float4*>(xr1),
           *reinterpret_cast<const float4*>(xr1 + 4), Ah1c0, Am1c0);
    split8(*reinterpret_cast<const float4*>(xr1 + 32),
           *reinterpret_cast<const float4*>(xr1 + 36), Ah1c1, Am1c1);
  }

  float b1[8], b2[8]; int i1[8];   // [s*4+r]
#pragma unroll
  for (int r = 0; r < 8; ++r) { b1[r] = 3.4e38f; b2[r] = 3.4e38f; i1[r] = 0; }

  const f32x4 kZero = {0.f, 0.f, 0.f, 0.f};

#pragma unroll 1
  for (int ph = 0; ph < 2; ++ph) {
    if (ph) __syncthreads();         // phase-0 readers done before overwrite
    {  // stage one phase: 64 KB, 512 thr x 8 x float4 (linear, coalesced)
      const float4* src = reinterpret_cast<const float4*>(F + ph * 4096);
      float4* dst = reinterpret_cast<float4*>(LB);
#pragma unroll
      for (int j = 0; j < 8; ++j) dst[tid + j * 512] = src[tid + j * 512];
    }
    __syncthreads();

#pragma unroll 4
    for (int t = 0; t < 16; ++t) {
      const f16x8 Bh0 = LB[t * 256 + lane];          // ds_read_b128, imm offs
      const f16x8 Bm0 = LB[t * 256 + 64 + lane];
      const f16x8 Bh1 = LB[t * 256 + 128 + lane];
      const f16x8 Bm1 = LB[t * 256 + 192 + lane];
      const int code = (ph * 16 + t) * 16 + row;
      const float nv = nrmL[code];                   // ds_read_b32 broadcast
      f32x4 p0, q0, p1, q1;
      __builtin_amdgcn_s_setprio(1);
      MFMA12(p0, q0, p1, q1, Bh0, Bm0, Bh1, Bm1);
      __builtin_amdgcn_s_setprio(0);
      SCORE4(p0, q0, p1, q1, code, nv);
    }
  }

  // Butterfly merge across the 16 rows (disjoint code subsets -> exact
  // 1st/2nd of union; cross-row ties -> gap 0 -> flagged -> exact fallback).
#pragma unroll
  for (int m = 1; m < 16; m <<= 1) {
#pragma unroll
    for (int r = 0; r < 8; ++r) {
      const float o1 = __shfl_xor(b1[r], m, 64);
      const int   oi = __shfl_xor(i1[r], m, 64);
      const float o2 = __shfl_xor(b2[r], m, 64);
      if (o1 < b1[r]) { b2[r] = fminf(b1[r], o2); b1[r] = o1; i1[r] = oi; }
      else            { b2[r] = fminf(b2[r], o1); }
    }
  }

  // Id writes + compact flag list (one atomic per wave).
  unsigned m32 = 0;
  if (row == 0) {   // lanes 0,16,32,48: each owns 8 queries (2 sets x 4 regs)
#pragma unroll
    for (int r = 0; r < 8; ++r) {
      const int qoff = (r >> 2) * 16 + kg * 4 + (r & 3);
      idf[qbase + qoff] = (float)i1[r];
      if (b2[r] - b1[r] < GUARD) m32 |= 1u << qoff;
    }
  }
  m32 |= __shfl_xor((int)m32, 16, 64);
  m32 |= __shfl_xor((int)m32, 32, 64);
  if (lane == 0 && m32) {
    int base = atomicAdd(cnt, __popc(m32));
    while (m32) {
      const int b = __ffs(m32) - 1;
      m32 &= m32 - 1;
      list[base++] = qbase + b;
    }
  }
}

// ---------------------------------------------------------------------------
// Fallback v3 (unchanged, proven): exact fp32 rescore, 16 flagged queries per
// block; lane = code, coalesced embed [d][K] reads; numerics bit-identical to
// the round-1 exact path.
// ---------------------------------------------------------------------------
__global__ __launch_bounds__(256) void vq_fallback_kernel(
    const float* __restrict__ x, const float* __restrict__ embed,
    const float* __restrict__ nrm, const int* __restrict__ cnt,
    const int* __restrict__ list, float* __restrict__ idf)
{
  __shared__ float x_lds[FB_Q * D];   // 4 KB
  __shared__ int   s_qidx[FB_Q];
  __shared__ float s_best[4][FB_Q];
  __shared__ int   s_bid[4][FB_Q];
  const int tid  = threadIdx.x;
  const int lane = tid & 63;
  const int wv   = tid >> 6;          // 0..3: codes wv*128 + {lane, lane+64}
  const int n = cnt[0];

  for (int qb = blockIdx.x * FB_Q; qb < n; qb += gridDim.x * FB_Q) {
    __syncthreads();   // previous batch's epilogue reads done before overwrite
    if (tid < FB_Q) {
      const int idx = qb + tid;
      s_qidx[tid] = list[idx < n ? idx : qb];  // pad with first-of-batch (dup-safe)
    }
    __syncthreads();
    {  // stage x rows: 16 q x 16 float4 = 256 loads, 1 per thread
      const int qj = tid >> 4, dq = tid & 15;
      *reinterpret_cast<float4*>(&x_lds[qj * D + dq * 4]) =
          *reinterpret_cast<const float4*>(x + (size_t)s_qidx[qj] * D + dq * 4);
    }
    __syncthreads();

    const int c0 = wv * 128 + lane;
    const int c1 = c0 + 64;
    float a0[FB_Q], a1[FB_Q];
#pragma unroll
    for (int i = 0; i < FB_Q; ++i) { a0[i] = 0.f; a1[i] = 0.f; }

#pragma unroll 4
    for (int ch = 0; ch < 16; ++ch) {   // 4 dims per chunk, d ascending
      const int d0 = ch * 4;
      const float e00 = embed[(d0 + 0) * K + c0];
      const float e01 = embed[(d0 + 0) * K + c1];
      const float e10 = embed[(d0 + 1) * K + c0];
      const float e11 = embed[(d0 + 1) * K + c1];
      const float e20 = embed[(d0 + 2) * K + c0];
      const float e21 = embed[(d0 + 2) * K + c1];
      const float e30 = embed[(d0 + 3) * K + c0];
      const float e31 = embed[(d0 + 3) * K + c1];
#pragma unroll
      for (int i = 0; i < FB_Q; ++i) {
        const float4 xv = *reinterpret_cast<const float4*>(&x_lds[i * D + d0]);
        a0[i] = fmaf(xv.x, e00, a0[i]);
        a0[i] = fmaf(xv.y, e10, a0[i]);
        a0[i] = fmaf(xv.z, e20, a0[i]);
        a0[i] = fmaf(xv.w, e30, a0[i]);
        a1[i] = fmaf(xv.x, e01, a1[i]);
        a1[i] = fmaf(xv.y, e11, a1[i]);
        a1[i] = fmaf(xv.z, e21, a1[i]);
        a1[i] = fmaf(xv.w, e31, a1[i]);
      }
    }

    const float nr0 = nrm[c0], nr1 = nrm[c1];
#pragma unroll
    for (int i = 0; i < FB_Q; ++i) {
      float best; int bid;
      const float s0 = fmaf(-2.f, a0[i], nr0);
      best = s0; bid = c0;                      // c0 < c1, visited first
      const float s1 = fmaf(-2.f, a1[i], nr1);
      if (s1 < best) { best = s1; bid = c1; }
#pragma unroll
      for (int off = 32; off > 0; off >>= 1) {
        const float s2 = __shfl_down(best, off, 64);
        const int   b2 = __shfl_down(bid, off, 64);
        if (s2 < best || (s2 == best && b2 < bid)) { best = s2; bid = b2; }
      }
      if (lane == 0) { s_best[wv][i] = best; s_bid[wv][i] = bid; }
    }
    __syncthreads();
    if (tid < FB_Q) {   // merge 4 waves, ascending wv = ascending code range
      float best = s_best[0][tid]; int bid = s_bid[0][tid];
#pragma unroll
      for (int w = 1; w < 4; ++w) {
        const float s = s_best[w][tid];
        if (s < best) { best = s; bid = s_bid[w][tid]; }  // tie keeps lower k
      }
      idf[s_qidx[tid]] = (float)bid;
    }
  }
}

// ---------------------------------------------------------------------------
// Gather (r17/r19 version, proven 13 µs): q = et[id], q_st, diff partials.
// ---------------------------------------------------------------------------
__global__ __launch_bounds__(256) void vq_gather_kernel(
    const float* __restrict__ x, const float* __restrict__ et,
    const float* __restrict__ idf, float* __restrict__ q,
    float* __restrict__ partial)
{
  const int tid = blockIdx.x * 256 + threadIdx.x;
  const int stride = gridDim.x * 256;
  float acc = 0.f;
  for (int idx = tid; idx < N_VEC * (D / 4); idx += stride) {
    const int v = idx >> 4;
    const int d4 = idx & 15;
    const int id = (int)idf[v];
    const float4 xv = reinterpret_cast<const float4*>(x)[idx];
    const float4 ev = reinterpret_cast<const float4*>(et)[(id << 4) + d4];
    const float e0 = ev.x - xv.x, e1 = ev.y - xv.y, e2 = ev.z - xv.z, e3 = ev.w - xv.w;
    acc += (e0 * e0 + e1 * e1) + (e2 * e2 + e3 * e3);
    reinterpret_cast<float4*>(q)[idx] = ev;
  }
  acc += __shfl_down(acc, 32, 64);
  acc += __shfl_down(acc, 16, 64);
  acc += __shfl_down(acc, 8, 64);
  acc += __shfl_down(acc, 4, 64);
  acc += __shfl_down(acc, 2, 64);
  acc += __shfl_down(acc, 1, 64);
  __shared__ float sred[4];
  if ((threadIdx.x & 63) == 0) sred[threadIdx.x >> 6] = acc;
  __syncthreads();
  if (threadIdx.x == 0)
    partial[blockIdx.x] = (sred[0] + sred[1]) + (sred[2] + sred[3]);
}

__global__ __launch_bounds__(256) void vq_finalize_kernel(
    const float* __restrict__ partial, float* __restrict__ out)
{
  float acc = 0.f;
  for (int i = threadIdx.x; i < NB_GATHER; i += 256) acc += partial[i];
  acc += __shfl_down(acc, 32, 64);
  acc += __shfl_down(acc, 16, 64);
  acc += __shfl_down(acc, 8, 64);
  acc += __shfl_down(acc, 4, 64);
  acc += __shfl_down(acc, 2, 64);
  acc += __shfl_down(acc, 1, 64);
  __shared__ float sred[4];
  if ((threadIdx.x & 63) == 0) sred[threadIdx.x >> 6] = acc;
  __syncthreads();
  if (threadIdx.x == 0)
    out[0] = ((sred[0] + sred[1]) + (sred[2] + sred[3])) * (1.0f / (float)(N_VEC * D));
}

extern "C" void kernel_launch(void* const* d_in, const int* in_sizes, int n_in,
                              void* d_out, int out_size, void* d_ws, size_t ws_size,
                              hipStream_t stream) {
  const float* x = (const float*)d_in[0];
  const float* embed = (const float*)d_in[1];
  float* out = (float*)d_out;
  float* q    = out;                 // [0, 8388608): q_st
  float* diff = out + 8388608;       // commitment loss scalar
  float* idf  = out + 8388609;       // emd_id as float [131072]

  float* ws = (float*)d_ws;          // layout (float idx):
  float* et      = ws;               // [0, 32768)       fp32 codebook rows
  float* nrm     = ws + 32768;       // [32768, 33312)   512 norms + 32 pad
  float* partial = ws + 33312;       // [33312, 35360)   diff partials
  int*   cnt     = (int*)(ws + 35360);         // flag counter
  int*   list    = (int*)(ws + 35368);         // flagged query indices
  f16x8* F = (f16x8*)(ws + 35368 + N_VEC);     // 128 KB packed hi/mid frags

  vq_prep_kernel<<<40, 64, 0, stream>>>(embed, et, nrm, F, cnt);
  vq_coarse_kernel<<<N_VEC / 256, 512, 0, stream>>>(x, F, nrm, idf, cnt, list);
  vq_fallback_kernel<<<1024, 256, 0, stream>>>(x, embed, nrm, cnt, list, idf);
  vq_gather_kernel<<<NB_GATHER, 256, 0, stream>>>(x, et, idf, q, partial);
  vq_finalize_kernel<<<1, 256, 0, stream>>>(partial, diff);
}